// Round 3
// baseline (104.593 us; speedup 1.0000x reference)
//
#include <hip/hip_runtime.h>
#include <hip/hip_bf16.h>

#define BSZ 2
#define NN  512
#define DD  128

// All inputs/outputs are FLOAT32 (reference is pure f32; round-2 NaN proved
// the buffers are not bf16 — see journal).
//
// Algorithm: exp(k_j + B_ij) = exp(B_ij) * exp(k_j), and the stabilizing max
// cancels in num/den. So:
//   num[b,i,:] = sum_j eb[i,j] * (exp(k[b,j,:]) * v[b,j,:])
//   den[b,i,:] = sum_j eb[i,j] *  exp(k[b,j,:])
// Two [512x512] @ [512x256] f32 GEMMs (268 MFLOP total) instead of 67M exps.

// ---------------------------------------------------------------------------
// K1: blocks 0..127   : QKV for 8 rows each (row m = b*NN+n), 128 threads
//     blocks 128..383 : eb = exp(B), 1024 elements per block
// Outputs (f32 in ws):
//   qs  [BSZ][NN][DD]       sigmoid(q)
//   ekc [BSZ][NN][2*DD]     c<128: exp(k)*v ; c>=128: exp(k)
//   eb  [NN][NN]            exp(B)
// ---------------------------------------------------------------------------
__global__ __launch_bounds__(128) void aft_k1(
    const float* __restrict__ x,
    const float* __restrict__ Wq, const float* __restrict__ bq,
    const float* __restrict__ Wk, const float* __restrict__ bk,
    const float* __restrict__ Wv, const float* __restrict__ bv,
    const float* __restrict__ Bm,
    float* __restrict__ qs, float* __restrict__ ekc, float* __restrict__ eb)
{
    const int blk = blockIdx.x;
    const int t   = threadIdx.x;

    if (blk < 128) {
        // ---- QKV for rows [blk*8, blk*8+8) ----
        __shared__ float xs[8][DD];
        const int r0 = blk * 8;
        #pragma unroll
        for (int r = 0; r < 8; ++r)
            xs[r][t] = x[(size_t)(r0 + r) * DD + t];
        __syncthreads();

        float aq[8], ak[8], av[8];
        const float bqv = bq[t], bkv = bk[t], bvv = bv[t];
        #pragma unroll
        for (int r = 0; r < 8; ++r) { aq[r] = bqv; ak[r] = bkv; av[r] = bvv; }

        #pragma unroll 4
        for (int d = 0; d < DD; ++d) {
            const float wq = Wq[d * DD + t];
            const float wk = Wk[d * DD + t];
            const float wv = Wv[d * DD + t];
            #pragma unroll
            for (int r = 0; r < 8; ++r) {
                const float xv = xs[r][d];
                aq[r] = fmaf(xv, wq, aq[r]);
                ak[r] = fmaf(xv, wk, ak[r]);
                av[r] = fmaf(xv, wv, av[r]);
            }
        }

        #pragma unroll
        for (int r = 0; r < 8; ++r) {
            const int m  = r0 + r;
            const float ek = __expf(ak[r]);
            qs[(size_t)m * DD + t] = 1.0f / (1.0f + __expf(-aq[r]));
            float* base = ekc + (size_t)m * (2 * DD);
            base[t]      = ek * av[r];   // numerator operand
            base[DD + t] = ek;           // denominator operand
        }
    } else {
        // ---- eb = exp(B), 1024 floats (256 float4) per block ----
        const int e = blk - 128;                      // 0..255
        const float4* s4 = (const float4*)Bm + (size_t)e * 256;
        float4*       d4 = (float4*)eb + (size_t)e * 256;
        #pragma unroll
        for (int r = 0; r < 2; ++r) {
            float4 v = s4[r * 128 + t];
            v.x = __expf(v.x); v.y = __expf(v.y);
            v.z = __expf(v.z); v.w = __expf(v.w);
            d4[r * 128 + t] = v;
        }
    }
}

// ---------------------------------------------------------------------------
// K2: partial GEMM  part[jc][b][i][c] = sum_{j in chunk jc} eb[i][j]*ekc[b][j][c]
// Grid 256 = (b:2) x (itile:32) x (jchunk:4); block 256 threads.
// Thread = one column c, 16 i-rows in registers. eb reads are wave-uniform
// (scalar loads); ekc reads are one coalesced dword per j.
// ---------------------------------------------------------------------------
__global__ __launch_bounds__(256) void aft_k2(
    const float* __restrict__ eb, const float* __restrict__ ekc,
    float* __restrict__ pnum, float* __restrict__ pden)
{
    const int blk = blockIdx.x;
    const int b   = blk & 1;
    const int it  = (blk >> 1) & 31;
    const int jc  = blk >> 6;          // 0..3
    const int c   = threadIdx.x;       // 0..255
    const int i0  = it * 16;
    const int j0  = jc * 128;

    const float* src = ekc + ((size_t)b * NN + j0) * (2 * DD) + c;
    const float* ebp = eb + (size_t)i0 * NN + j0;

    float acc[16];
    #pragma unroll
    for (int ii = 0; ii < 16; ++ii) acc[ii] = 0.0f;

    for (int j = 0; j < 128; j += 4) {
        const float w0 = src[0 * 2 * DD];
        const float w1 = src[1 * 2 * DD];
        const float w2 = src[2 * 2 * DD];
        const float w3 = src[3 * 2 * DD];
        src += 4 * 2 * DD;
        #pragma unroll
        for (int ii = 0; ii < 16; ++ii) {
            const float4 e = *(const float4*)(ebp + (size_t)ii * NN + j);
            acc[ii] = fmaf(e.w, w3, fmaf(e.z, w2, fmaf(e.y, w1, fmaf(e.x, w0, acc[ii]))));
        }
    }

    float*      dst = (c < DD) ? pnum : pden;
    const int   d   = c & (DD - 1);
    const size_t o  = ((size_t)jc * BSZ + b) * NN * DD + (size_t)i0 * DD + d;
    #pragma unroll
    for (int ii = 0; ii < 16; ++ii)
        dst[o + (size_t)ii * DD] = acc[ii];
}

// ---------------------------------------------------------------------------
// K3: out = f32( qs * (sum pnum) / (sum pden) ), flat index matches [b][i][d]
// ---------------------------------------------------------------------------
__global__ __launch_bounds__(256) void aft_k3(
    const float* __restrict__ qs, const float* __restrict__ pnum,
    const float* __restrict__ pden, float* __restrict__ out)
{
    const int idx = blockIdx.x * 256 + threadIdx.x;   // grid 512 -> 131072
    const int S   = BSZ * NN * DD;                    // 131072
    const float n0 = pnum[idx] + pnum[idx + S] + pnum[idx + 2 * S] + pnum[idx + 3 * S];
    const float d0 = pden[idx] + pden[idx + S] + pden[idx + 2 * S] + pden[idx + 3 * S];
    out[idx] = qs[idx] * n0 / d0;
}

extern "C" void kernel_launch(void* const* d_in, const int* in_sizes, int n_in,
                              void* d_out, int out_size, void* d_ws, size_t ws_size,
                              hipStream_t stream) {
    const float* x  = (const float*)d_in[0];
    const float* Wq = (const float*)d_in[1];
    const float* bq = (const float*)d_in[2];
    const float* Wk = (const float*)d_in[3];
    const float* bk = (const float*)d_in[4];
    const float* Wv = (const float*)d_in[5];
    const float* bv = (const float*)d_in[6];
    const float* Bm = (const float*)d_in[7];
    float* out = (float*)d_out;

    // ws partition (floats): qs | ekc | eb | pnum | pden  (~6.8 MB total)
    float* qs   = (float*)d_ws;
    float* ekc  = qs   + (size_t)BSZ * NN * DD;        // 131072
    float* eb   = ekc  + (size_t)BSZ * NN * 2 * DD;    // 262144
    float* pnum = eb   + (size_t)NN * NN;              // 262144
    float* pden = pnum + (size_t)4 * BSZ * NN * DD;    // 524288

    aft_k1<<<dim3(384), dim3(128), 0, stream>>>(
        x, Wq, bq, Wk, bk, Wv, bv, Bm, qs, ekc, eb);
    aft_k2<<<dim3(256), dim3(256), 0, stream>>>(eb, ekc, pnum, pden);
    aft_k3<<<dim3(512), dim3(256), 0, stream>>>(qs, pnum, pden, out);
}